// Round 3
// baseline (2320.468 us; speedup 1.0000x reference)
//
#include <hip/hip_runtime.h>
#include <hip/hip_bf16.h>
#include <stdint.h>

// Problem constants: B=4, S=512, E=768, H=12, D=64, L=12, FF=3072, M = B*S = 2048
#define LAYERS 12
#define M_ROWS 2048
#define E_DIM 768
#define FF_DIM 3072
#define QKV_DIM 2304
#define SCALE_INV 0.036084391824351615f  // 1/sqrt(768)

typedef __hip_bfloat16 bf16;
typedef __attribute__((ext_vector_type(8))) __bf16 bf16x8;
typedef __attribute__((ext_vector_type(4))) float f32x4;

__device__ __forceinline__ float bf2f(bf16 v) { return __bfloat162float(v); }
__device__ __forceinline__ bf16 f2bf(float v) { return __float2bfloat16(v); }

__device__ __forceinline__ float gelu_f(float x) {
  return 0.5f * x * (1.0f + erff(x * 0.70710678118654752f));
}

// async 16B global->LDS (direct-to-shared DMA). LDS dest must be
// wave-uniform base + lane*16 — all call sites honor that.
__device__ __forceinline__ void glds16(const bf16* g, bf16* l) {
  __builtin_amdgcn_global_load_lds(
      (const __attribute__((address_space(1))) void*)g,
      (__attribute__((address_space(3))) void*)l, 16, 0, 0);
}

// ---------------------------------------------------------------------------
// Batched weight transpose+convert for ALL layers: fp32 [K][N] -> bf16 [N][K].
// 6912 tiles per layer * 12 layers = 82944 blocks.
// ---------------------------------------------------------------------------
__global__ __launch_bounds__(256) void transpose_k(
    const float* __restrict__ w0, const float* __restrict__ w1,
    const float* __restrict__ w2, const float* __restrict__ w3,
    bf16* __restrict__ t0, bf16* __restrict__ t1,
    bf16* __restrict__ t2, bf16* __restrict__ t3)
{
  __shared__ float T[32][33];
  int l = blockIdx.x / 6912;
  int bid = blockIdx.x - l * 6912;
  const float* src; bf16* dst; int K, N, tile;
  if (bid < 1728)      { src = w0 + (size_t)l * 768 * 2304; dst = t0 + (size_t)l * 768 * 2304; K = 768;  N = 2304; tile = bid; }
  else if (bid < 2304) { src = w1 + (size_t)l * 768 * 768;  dst = t1 + (size_t)l * 768 * 768;  K = 768;  N = 768;  tile = bid - 1728; }
  else if (bid < 4608) { src = w2 + (size_t)l * 768 * 3072; dst = t2 + (size_t)l * 768 * 3072; K = 768;  N = 3072; tile = bid - 2304; }
  else                 { src = w3 + (size_t)l * 3072 * 768; dst = t3 + (size_t)l * 3072 * 768; K = 3072; N = 768;  tile = bid - 4608; }
  int tilesN = N >> 5;
  int tk = tile / tilesN;
  int tn = tile - tk * tilesN;
  int tx = threadIdx.x & 31, ty = threadIdx.x >> 5;
  int k0 = tk << 5, n0 = tn << 5;
#pragma unroll
  for (int i = 0; i < 4; i++)
    T[ty + i * 8][tx] = src[(size_t)(k0 + ty + i * 8) * N + n0 + tx];
  __syncthreads();
#pragma unroll
  for (int i = 0; i < 4; i++)
    dst[(size_t)(n0 + ty + i * 8) * K + k0 + tx] = f2bf(T[tx][ty + i * 8]);
}

// ---------------------------------------------------------------------------
// Row-stats helper: block=256, row length 768 (3 vals/thread already summed
// into s/sq by caller). Barrier-safe for repeated calls.
// ---------------------------------------------------------------------------
__device__ __forceinline__ void rowstats(float s, float sq, float* red, int tid,
                                         float& mean, float& rstd) {
#pragma unroll
  for (int off = 32; off; off >>= 1) {
    s += __shfl_xor(s, off);
    sq += __shfl_xor(sq, off);
  }
  __syncthreads();           // previous users of red[] are done
  int wv = tid >> 6;
  if ((tid & 63) == 0) { red[wv] = s; red[4 + wv] = sq; }
  __syncthreads();
  s  = red[0] + red[1] + red[2] + red[3];
  sq = red[4] + red[5] + red[6] + red[7];
  mean = s * (1.0f / 768.0f);
  float var = sq * (1.0f / 768.0f) - mean * mean;
  rstd = rsqrtf(var + 1e-5f);
}

// Plain LN: out_bf16 = LN(in)*g+b   (used once, for layer-0 LN1)
__global__ __launch_bounds__(256) void ln_k(
    const float* in, const float* gamma, const float* beta, bf16* outp)
{
  __shared__ float red[8];
  int row = blockIdx.x, tid = threadIdx.x;
  const float* x = in + (size_t)row * 768;
  float v[3]; float s = 0.f, sq = 0.f;
#pragma unroll
  for (int j = 0; j < 3; j++) {
    v[j] = x[tid + j * 256];
    s += v[j]; sq += v[j] * v[j];
  }
  float mean, rstd;
  rowstats(s, sq, red, tid, mean, rstd);
#pragma unroll
  for (int j = 0; j < 3; j++) {
    int c = tid + j * 256;
    outp[(size_t)row * 768 + c] = f2bf((v[j] - mean) * rstd * gamma[c] + beta[c]);
  }
}

// Fused: r1 = LN2(in)*g2+b2 + xres;  hb = bf16(LN3(r1)*g3+b3)
__global__ __launch_bounds__(256) void ln23_k(
    const float* in, const float* g2, const float* b2, const float* xres,
    float* r1out, const float* g3, const float* b3, bf16* hbout)
{
  __shared__ float red[8];
  int row = blockIdx.x, tid = threadIdx.x;
  const float* x = in + (size_t)row * 768;
  float v[3]; float s = 0.f, sq = 0.f;
#pragma unroll
  for (int j = 0; j < 3; j++) {
    v[j] = x[tid + j * 256];
    s += v[j]; sq += v[j] * v[j];
  }
  float mean, rstd;
  rowstats(s, sq, red, tid, mean, rstd);
  s = 0.f; sq = 0.f;
#pragma unroll
  for (int j = 0; j < 3; j++) {
    int c = tid + j * 256;
    v[j] = (v[j] - mean) * rstd * g2[c] + b2[c] + xres[(size_t)row * 768 + c];
    r1out[(size_t)row * 768 + c] = v[j];
    s += v[j]; sq += v[j] * v[j];
  }
  rowstats(s, sq, red, tid, mean, rstd);
#pragma unroll
  for (int j = 0; j < 3; j++) {
    int c = tid + j * 256;
    hbout[(size_t)row * 768 + c] = f2bf((v[j] - mean) * rstd * g3[c] + b3[c]);
  }
}

// Fused: xio = LN4(in)*g4+b4 + r1 + xio;  if g1n: hb = bf16(LN1n(xio)*g1n+b1n)
__global__ __launch_bounds__(256) void ln41_k(
    const float* in, const float* g4, const float* b4, const float* r1,
    float* xio, const float* g1n, const float* b1n, bf16* hbout)
{
  __shared__ float red[8];
  int row = blockIdx.x, tid = threadIdx.x;
  const float* x = in + (size_t)row * 768;
  float v[3]; float s = 0.f, sq = 0.f;
#pragma unroll
  for (int j = 0; j < 3; j++) {
    v[j] = x[tid + j * 256];
    s += v[j]; sq += v[j] * v[j];
  }
  float mean, rstd;
  rowstats(s, sq, red, tid, mean, rstd);
  s = 0.f; sq = 0.f;
#pragma unroll
  for (int j = 0; j < 3; j++) {
    int c = tid + j * 256;
    size_t idx = (size_t)row * 768 + c;
    v[j] = (v[j] - mean) * rstd * g4[c] + b4[c] + r1[idx] + xio[idx];
    xio[idx] = v[j];
    s += v[j]; sq += v[j] * v[j];
  }
  if (g1n == nullptr) return;
  rowstats(s, sq, red, tid, mean, rstd);
#pragma unroll
  for (int j = 0; j < 3; j++) {
    int c = tid + j * 256;
    hbout[(size_t)row * 768 + c] = f2bf((v[j] - mean) * rstd * g1n[c] + b1n[c]);
  }
}

// ---------------------------------------------------------------------------
// 128x128 MFMA GEMM with global_load_lds staging (m97 structure).
// 4 waves, each 64x64 (4x4 16x16x32 tiles). BK=32.
// OUT_MODE: 2 = bf16+GELU, 3 = split-QKV (q,k [B][H][S][D]; v [B][H][D][S]).
// ---------------------------------------------------------------------------
template<int OUT_MODE>
__global__ __launch_bounds__(256) void gemm128_k(
    const bf16* __restrict__ A, const bf16* __restrict__ BT,
    const float* __restrict__ bias, void* __restrict__ Cout,
    bf16* __restrict__ qo, bf16* __restrict__ ko, bf16* __restrict__ vo,
    int N, int K, int nTilesN)
{
  __shared__ __align__(16) bf16 Als[128 * 32];
  __shared__ __align__(16) bf16 Bls[128 * 32];
  int tid = threadIdx.x;
  int lane = tid & 63, w = tid >> 6;
  int l15 = lane & 15, l4 = lane >> 4;
  int tm = blockIdx.x / nTilesN;
  int tn = blockIdx.x - tm * nTilesN;
  int m0 = tm << 7, n0 = tn << 7;
  int wm = (w >> 1) << 6, wn = (w & 1) << 6;
  const bf16* Ag = A + (size_t)m0 * K;
  const bf16* Bg = BT + (size_t)n0 * K;
  int srow = tid >> 2;            // 0..63
  int scol = (tid & 3) * 8;
  f32x4 acc[4][4] = {};
  for (int k0 = 0; k0 < K; k0 += 32) {
    __syncthreads();             // prior LDS reads complete
    glds16(Ag + (size_t)srow * K + k0 + scol,        Als + tid * 8);
    glds16(Ag + (size_t)(srow + 64) * K + k0 + scol, Als + 2048 + tid * 8);
    glds16(Bg + (size_t)srow * K + k0 + scol,        Bls + tid * 8);
    glds16(Bg + (size_t)(srow + 64) * K + k0 + scol, Bls + 2048 + tid * 8);
    __syncthreads();             // vmcnt(0) drained by barrier
    int ko8 = l4 * 8;
    bf16x8 af[4], bfr[4];
#pragma unroll
    for (int i = 0; i < 4; i++)
      af[i] = *(const bf16x8*)&Als[(wm + i * 16 + l15) * 32 + ko8];
#pragma unroll
    for (int j = 0; j < 4; j++)
      bfr[j] = *(const bf16x8*)&Bls[(wn + j * 16 + l15) * 32 + ko8];
#pragma unroll
    for (int i = 0; i < 4; i++)
#pragma unroll
      for (int j = 0; j < 4; j++)
        acc[i][j] = __builtin_amdgcn_mfma_f32_16x16x32_bf16(af[i], bfr[j], acc[i][j], 0, 0, 0);
  }
#pragma unroll
  for (int i = 0; i < 4; i++) {
    int mbase = m0 + wm + i * 16 + (l4 << 2);
#pragma unroll
    for (int j = 0; j < 4; j++) {
      int n = n0 + wn + j * 16 + l15;
      float bvs = bias[n];
      if (OUT_MODE == 3) {
        int h = n / 192;
        int rm = n - h * 192;
        int d = rm / 3;
        int t = rm - d * 3;
#pragma unroll
        for (int rg = 0; rg < 4; rg++) {
          int m = mbase + rg;
          float val = acc[i][j][rg] + bvs;
          int b = m >> 9, sIdx = m & 511;
          int bh = b * 12 + h;
          if (t == 2)
            vo[(size_t)((bh << 6) + d) * 512 + sIdx] = f2bf(val);       // [B][H][D][S]
          else {
            bf16* dsts = (t == 0) ? qo : ko;
            dsts[(size_t)((bh << 9) + sIdx) * 64 + d] = f2bf(val);      // [B][H][S][D]
          }
        }
      } else {
#pragma unroll
        for (int rg = 0; rg < 4; rg++) {
          int m = mbase + rg;
          float val = acc[i][j][rg] + bvs;
          ((bf16*)Cout)[(size_t)m * N + n] = f2bf(gelu_f(val));
        }
      }
    }
  }
}

// ---------------------------------------------------------------------------
// 64x64 MFMA GEMM with global_load_lds staging, fp32 output (proj / FF2).
// 4 waves, each 32x32 (2x2 tiles). BK=32.
// ---------------------------------------------------------------------------
__global__ __launch_bounds__(256) void gemm64_k(
    const bf16* __restrict__ A, const bf16* __restrict__ BT,
    const float* __restrict__ bias, float* __restrict__ Cout,
    int N, int K, int nTilesN)
{
  __shared__ __align__(16) bf16 Als[64 * 32];
  __shared__ __align__(16) bf16 Bls[64 * 32];
  int tid = threadIdx.x;
  int lane = tid & 63, w = tid >> 6;
  int l15 = lane & 15, l4 = lane >> 4;
  int tm = blockIdx.x / nTilesN;
  int tn = blockIdx.x - tm * nTilesN;
  int m0 = tm << 6, n0 = tn << 6;
  int wm = (w >> 1) << 5, wn = (w & 1) << 5;
  const bf16* Ag = A + (size_t)m0 * K;
  const bf16* Bg = BT + (size_t)n0 * K;
  int srow = tid >> 2;
  int scol = (tid & 3) * 8;
  f32x4 acc[2][2] = {};
  for (int k0 = 0; k0 < K; k0 += 32) {
    __syncthreads();
    glds16(Ag + (size_t)srow * K + k0 + scol, Als + tid * 8);
    glds16(Bg + (size_t)srow * K + k0 + scol, Bls + tid * 8);
    __syncthreads();
    int ko8 = l4 * 8;
    bf16x8 af[2], bfr[2];
#pragma unroll
    for (int i = 0; i < 2; i++)
      af[i] = *(const bf16x8*)&Als[(wm + i * 16 + l15) * 32 + ko8];
#pragma unroll
    for (int j = 0; j < 2; j++)
      bfr[j] = *(const bf16x8*)&Bls[(wn + j * 16 + l15) * 32 + ko8];
#pragma unroll
    for (int i = 0; i < 2; i++)
#pragma unroll
      for (int j = 0; j < 2; j++)
        acc[i][j] = __builtin_amdgcn_mfma_f32_16x16x32_bf16(af[i], bfr[j], acc[i][j], 0, 0, 0);
  }
#pragma unroll
  for (int i = 0; i < 2; i++) {
    int mbase = m0 + wm + i * 16 + (l4 << 2);
#pragma unroll
    for (int j = 0; j < 2; j++) {
      int n = n0 + wn + j * 16 + l15;
      float bvs = bias[n];
#pragma unroll
      for (int rg = 0; rg < 4; rg++)
        Cout[(size_t)(mbase + rg) * N + n] = acc[i][j][rg] + bvs;
    }
  }
}

// ---------------------------------------------------------------------------
// MFMA flash attention (unchanged from R1). Block = (b,h) x 64 query rows.
// ---------------------------------------------------------------------------
#define PSTR 80
__global__ __launch_bounds__(256) void attn_k(
    const bf16* __restrict__ q, const bf16* __restrict__ k,
    const bf16* __restrict__ vT, bf16* __restrict__ o)
{
  __shared__ __align__(16) bf16 Kls[64 * 64];
  __shared__ __align__(16) bf16 Vls[64 * 64];
  __shared__ __align__(16) bf16 Pls[4][16 * PSTR];
  int tid = threadIdx.x;
  int lane = tid & 63, w = tid >> 6;
  int l15 = lane & 15, l4 = lane >> 4;
  int qt = blockIdx.x & 7;
  int bh = blockIdx.x >> 3;
  size_t base = (size_t)bh * 32768;

  const bf16* qrowp = q + base + (size_t)(qt * 64 + w * 16 + l15) * 64 + l4 * 8;
  bf16x8 qf0 = *(const bf16x8*)qrowp;
  bf16x8 qf1 = *(const bf16x8*)(qrowp + 32);

  float mrow[4] = {-1e30f, -1e30f, -1e30f, -1e30f};
  float lsum[4] = {0.f, 0.f, 0.f, 0.f};
  f32x4 Oacc[4] = {};
  const f32x4 zed = {0.f, 0.f, 0.f, 0.f};
  bf16* pw = &Pls[w][0];

  for (int kt = 0; kt < 8; kt++) {
    __syncthreads();
#pragma unroll
    for (int rep = 0; rep < 2; rep++) {
      int c = tid + rep * 256;
      int row = c >> 3, col8 = (c & 7) * 8;
      *(uint4*)&Kls[row * 64 + col8] =
          *(const uint4*)(k + base + (size_t)(kt * 64 + row) * 64 + col8);
      *(uint4*)&Vls[row * 64 + col8] =
          *(const uint4*)(vT + base + (size_t)row * 512 + kt * 64 + col8);
    }
    __syncthreads();
    f32x4 e[4];
#pragma unroll
    for (int jt = 0; jt < 4; jt++) {
      bf16x8 kf0 = *(const bf16x8*)&Kls[(jt * 16 + l15) * 64 + l4 * 8];
      bf16x8 kf1 = *(const bf16x8*)&Kls[(jt * 16 + l15) * 64 + l4 * 8 + 32];
      e[jt] = __builtin_amdgcn_mfma_f32_16x16x32_bf16(qf0, kf0, zed, 0, 0, 0);
      e[jt] = __builtin_amdgcn_mfma_f32_16x16x32_bf16(qf1, kf1, e[jt], 0, 0, 0);
    }
    float al[4];
#pragma unroll
    for (int rg = 0; rg < 4; rg++) {
      float mn = fmaxf(fmaxf(e[0][rg], e[1][rg]), fmaxf(e[2][rg], e[3][rg]));
#pragma unroll
      for (int off = 1; off < 16; off <<= 1) mn = fmaxf(mn, __shfl_xor(mn, off));
      float mnew = fmaxf(mrow[rg], mn);
      al[rg] = __expf(mrow[rg] - mnew);
      mrow[rg] = mnew;
    }
    float rs[4] = {0.f, 0.f, 0.f, 0.f};
#pragma unroll
    for (int jt = 0; jt < 4; jt++)
#pragma unroll
      for (int rg = 0; rg < 4; rg++) {
        float p = __expf(e[jt][rg] - mrow[rg]);
        rs[rg] += p;
        pw[(l4 * 4 + rg) * PSTR + jt * 16 + l15] = f2bf(p);
      }
#pragma unroll
    for (int rg = 0; rg < 4; rg++) {
#pragma unroll
      for (int off = 1; off < 16; off <<= 1) rs[rg] += __shfl_xor(rs[rg], off);
      lsum[rg] = lsum[rg] * al[rg] + rs[rg];
    }
#pragma unroll
    for (int dt = 0; dt < 4; dt++)
#pragma unroll
      for (int rg = 0; rg < 4; rg++) Oacc[dt][rg] *= al[rg];
    bf16x8 pf0 = *(const bf16x8*)&pw[l15 * PSTR + l4 * 8];
    bf16x8 pf1 = *(const bf16x8*)&pw[l15 * PSTR + l4 * 8 + 32];
#pragma unroll
    for (int dt = 0; dt < 4; dt++) {
      bf16x8 vf0 = *(const bf16x8*)&Vls[(dt * 16 + l15) * 64 + l4 * 8];
      bf16x8 vf1 = *(const bf16x8*)&Vls[(dt * 16 + l15) * 64 + l4 * 8 + 32];
      Oacc[dt] = __builtin_amdgcn_mfma_f32_16x16x32_bf16(pf0, vf0, Oacc[dt], 0, 0, 0);
      Oacc[dt] = __builtin_amdgcn_mfma_f32_16x16x32_bf16(pf1, vf1, Oacc[dt], 0, 0, 0);
    }
  }
  int b = bh / 12, h = bh - b * 12;
#pragma unroll
  for (int rg = 0; rg < 4; rg++) {
    int qrow = qt * 64 + w * 16 + l4 * 4 + rg;
    float inv = SCALE_INV / lsum[rg];
    size_t rowoff = (size_t)(b * 512 + qrow) * 768 + h * 64;
#pragma unroll
    for (int dt = 0; dt < 4; dt++)
      o[rowoff + dt * 16 + l15] = f2bf(Oacc[dt][rg] * inv);
  }
}

// ---------------------------------------------------------------------------
extern "C" void kernel_launch(void* const* d_in, const int* in_sizes, int n_in,
                              void* d_out, int out_size, void* d_ws, size_t ws_size,
                              hipStream_t stream)
{
  const float* x    = (const float*)d_in[0];
  const float* Wqkv = (const float*)d_in[1];
  const float* bqkv = (const float*)d_in[2];
  const float* Wp   = (const float*)d_in[3];
  const float* bp   = (const float*)d_in[4];
  const float* W1   = (const float*)d_in[5];
  const float* b1   = (const float*)d_in[6];
  const float* W2   = (const float*)d_in[7];
  const float* b2   = (const float*)d_in[8];
  const float* g1  = (const float*)d_in[9];
  const float* be1 = (const float*)d_in[10];
  const float* g2  = (const float*)d_in[11];
  const float* be2 = (const float*)d_in[12];
  const float* g3  = (const float*)d_in[13];
  const float* be3 = (const float*)d_in[14];
  const float* g4  = (const float*)d_in[15];
  const float* be4 = (const float*)d_in[16];
  float* xout = (float*)d_out;

  char* ws = (char*)d_ws;
  size_t off = 0;
  auto alloc = [&](size_t bytes) -> char* {
    char* p = ws + off;
    off += (bytes + 255) & ~(size_t)255;
    return p;
  };
  const size_t NTOK = (size_t)M_ROWS * E_DIM;
  bf16*  qb  = (bf16*)alloc(NTOK * 2);
  bf16*  kb  = (bf16*)alloc(NTOK * 2);
  bf16*  vb  = (bf16*)alloc(NTOK * 2);   // V^T [B][H][D][S]
  bf16*  hb  = (bf16*)alloc(NTOK * 2);
  bf16*  ob  = (bf16*)alloc(NTOK * 2);
  bf16*  f1b = (bf16*)alloc((size_t)M_ROWS * FF_DIM * 2);
  float* tmp = (float*)alloc(NTOK * 4);
  float* r1  = (float*)alloc(NTOK * 4);
  // all-layer transposed weights (bf16 [N][K])
  bf16*  tq  = (bf16*)alloc((size_t)LAYERS * 768 * 2304 * 2);
  bf16*  tp  = (bf16*)alloc((size_t)LAYERS * 768 * 768 * 2);
  bf16*  t1  = (bf16*)alloc((size_t)LAYERS * 768 * 3072 * 2);
  bf16*  t2  = (bf16*)alloc((size_t)LAYERS * 3072 * 768 * 2);
  if (off > ws_size) {
    hipMemsetAsync(d_out, 0x7f, (size_t)out_size * 4, stream);
    return;
  }

  hipMemcpyAsync(d_out, x, (size_t)out_size * 4, hipMemcpyDeviceToDevice, stream);

  // all weight transposes up-front, one launch
  transpose_k<<<6912 * LAYERS, 256, 0, stream>>>(Wqkv, Wp, W1, W2, tq, tp, t1, t2);

  // layer-0 LN1
  ln_k<<<2048, 256, 0, stream>>>(xout, g1, be1, hb);

  for (int l = 0; l < LAYERS; l++) {
    const bf16* tql = tq + (size_t)l * 768 * 2304;
    const bf16* tpl = tp + (size_t)l * 768 * 768;
    const bf16* t1l = t1 + (size_t)l * 768 * 3072;
    const bf16* t2l = t2 + (size_t)l * 3072 * 768;

    // qkv = hb @ Wqkv + bqkv  (288 blocks)
    gemm128_k<3><<<16 * 18, 256, 0, stream>>>(hb, tql, bqkv + (size_t)l * QKV_DIM,
                                              nullptr, qb, kb, vb, QKV_DIM, 768, 18);
    attn_k<<<384, 256, 0, stream>>>(qb, kb, vb, ob);
    // proj: tmp = ob @ Wp + bp  (384 blocks)
    gemm64_k<<<32 * 12, 256, 0, stream>>>(ob, tpl, bp + (size_t)l * 768,
                                          tmp, 768, 768, 12);
    // r1 = LN2(tmp)+x ; hb = LN3(r1)
    ln23_k<<<2048, 256, 0, stream>>>(tmp, g2 + l * 768, be2 + l * 768, xout,
                                     r1, g3 + l * 768, be3 + l * 768, hb);
    // f1 = gelu(hb @ W1 + b1)  (384 blocks)
    gemm128_k<2><<<16 * 24, 256, 0, stream>>>(hb, t1l, b1 + (size_t)l * FF_DIM,
                                              f1b, nullptr, nullptr, nullptr, FF_DIM, 768, 24);
    // tmp = f1 @ W2 + b2  (384 blocks)
    gemm64_k<<<32 * 12, 256, 0, stream>>>(f1b, t2l, b2 + (size_t)l * 768,
                                          tmp, 768, 3072, 12);
    // x = x + LN4(tmp) + r1 ; hb = LN1_{l+1}(x) unless last layer
    const float* g1n  = (l + 1 < LAYERS) ? g1 + (l + 1) * 768 : nullptr;
    const float* be1n = (l + 1 < LAYERS) ? be1 + (l + 1) * 768 : nullptr;
    ln41_k<<<2048, 256, 0, stream>>>(tmp, g4 + l * 768, be4 + l * 768, r1,
                                     xout, g1n, be1n, hb);
  }
}

// Round 4
// 2231.530 us; speedup vs baseline: 1.0399x; 1.0399x over previous
//
#include <hip/hip_runtime.h>
#include <hip/hip_bf16.h>
#include <stdint.h>

// Problem constants: B=4, S=512, E=768, H=12, D=64, L=12, FF=3072, M = B*S = 2048
#define LAYERS 12
#define M_ROWS 2048
#define E_DIM 768
#define FF_DIM 3072
#define QKV_DIM 2304
#define SCALE_INV 0.036084391824351615f  // 1/sqrt(768)

typedef __hip_bfloat16 bf16;
typedef __attribute__((ext_vector_type(8))) __bf16 bf16x8;
typedef __attribute__((ext_vector_type(4))) float f32x4;

__device__ __forceinline__ float bf2f(bf16 v) { return __bfloat162float(v); }
__device__ __forceinline__ bf16 f2bf(float v) { return __float2bfloat16(v); }

__device__ __forceinline__ float gelu_f(float x) {
  return 0.5f * x * (1.0f + erff(x * 0.70710678118654752f));
}

// ---------------------------------------------------------------------------
// Weight transpose+convert, ALL layers: fp32 [K][N] -> bf16 [N][K].
// 64x64 tiles; reads 16B/lane fp32, writes 32B/thread bf16 (128B per 4-lane
// group, fully coalesced). 1728 tiles/layer * 12 = 20736 blocks.
// ---------------------------------------------------------------------------
__global__ __launch_bounds__(256) void transpose_k(
    const float* __restrict__ w0, const float* __restrict__ w1,
    const float* __restrict__ w2, const float* __restrict__ w3,
    bf16* __restrict__ t0, bf16* __restrict__ t1,
    bf16* __restrict__ t2, bf16* __restrict__ t3)
{
  __shared__ float T[64][68];   // [n][k], stride 68 -> 16B-aligned rows
  int l = blockIdx.x / 1728;
  int bid = blockIdx.x - l * 1728;
  const float* src; bf16* dst; int K, N, tile;
  if (bid < 432)      { src = w0 + (size_t)l * 768 * 2304; dst = t0 + (size_t)l * 768 * 2304; K = 768;  N = 2304; tile = bid; }
  else if (bid < 576) { src = w1 + (size_t)l * 768 * 768;  dst = t1 + (size_t)l * 768 * 768;  K = 768;  N = 768;  tile = bid - 432; }
  else if (bid < 1152){ src = w2 + (size_t)l * 768 * 3072; dst = t2 + (size_t)l * 768 * 3072; K = 768;  N = 3072; tile = bid - 576; }
  else                { src = w3 + (size_t)l * 3072 * 768; dst = t3 + (size_t)l * 3072 * 768; K = 3072; N = 768;  tile = bid - 1152; }
  int tilesN = N >> 6;
  int tk = tile / tilesN;
  int tn = tile - tk * tilesN;
  int k0 = tk << 6, n0 = tn << 6;
  int tid = threadIdx.x;
  int tr = tid >> 2;            // 0..63
  int tc = (tid & 3) * 16;      // 0,16,32,48
  // load: row k = k0+tr, cols n0+tc..tc+15 (4x float4)
#pragma unroll
  for (int i = 0; i < 4; i++) {
    float4 f4 = *(const float4*)&src[(size_t)(k0 + tr) * N + n0 + tc + i * 4];
    T[tc + i * 4 + 0][tr] = f4.x;
    T[tc + i * 4 + 1][tr] = f4.y;
    T[tc + i * 4 + 2][tr] = f4.z;
    T[tc + i * 4 + 3][tr] = f4.w;
  }
  __syncthreads();
  // store: row n = n0+tr, cols k0+tc..tc+15 -> 16 bf16 = 32B contiguous
  bf16 outv[16];
#pragma unroll
  for (int i = 0; i < 4; i++) {
    float4 f4 = *(const float4*)&T[tr][tc + i * 4];
    outv[i * 4 + 0] = f2bf(f4.x);
    outv[i * 4 + 1] = f2bf(f4.y);
    outv[i * 4 + 2] = f2bf(f4.z);
    outv[i * 4 + 3] = f2bf(f4.w);
  }
  *(uint4*)&dst[(size_t)(n0 + tr) * K + k0 + tc] = *(uint4*)&outv[0];
  *(uint4*)&dst[(size_t)(n0 + tr) * K + k0 + tc + 8] = *(uint4*)&outv[8];
}

// ---------------------------------------------------------------------------
// Row-stats helper: block=256, row length 768.
// ---------------------------------------------------------------------------
__device__ __forceinline__ void rowstats(float s, float sq, float* red, int tid,
                                         float& mean, float& rstd) {
#pragma unroll
  for (int off = 32; off; off >>= 1) {
    s += __shfl_xor(s, off);
    sq += __shfl_xor(sq, off);
  }
  __syncthreads();
  int wv = tid >> 6;
  if ((tid & 63) == 0) { red[wv] = s; red[4 + wv] = sq; }
  __syncthreads();
  s  = red[0] + red[1] + red[2] + red[3];
  sq = red[4] + red[5] + red[6] + red[7];
  mean = s * (1.0f / 768.0f);
  float var = sq * (1.0f / 768.0f) - mean * mean;
  rstd = rsqrtf(var + 1e-5f);
}

// Plain LN: out_bf16 = LN(in)*g+b  (layer-0 LN1 only)
__global__ __launch_bounds__(256) void ln_k(
    const float* in, const float* gamma, const float* beta, bf16* outp)
{
  __shared__ float red[8];
  int row = blockIdx.x, tid = threadIdx.x;
  const float* x = in + (size_t)row * 768;
  float v[3]; float s = 0.f, sq = 0.f;
#pragma unroll
  for (int j = 0; j < 3; j++) {
    v[j] = x[tid + j * 256];
    s += v[j]; sq += v[j] * v[j];
  }
  float mean, rstd;
  rowstats(s, sq, red, tid, mean, rstd);
#pragma unroll
  for (int j = 0; j < 3; j++) {
    int c = tid + j * 256;
    outp[(size_t)row * 768 + c] = f2bf((v[j] - mean) * rstd * gamma[c] + beta[c]);
  }
}

// Fused: r1 = LN2(in)*g2+b2 + xres;  hb = bf16(LN3(r1)*g3+b3)
__global__ __launch_bounds__(256) void ln23_k(
    const float* in, const float* g2, const float* b2, const float* xres,
    float* r1out, const float* g3, const float* b3, bf16* hbout)
{
  __shared__ float red[8];
  int row = blockIdx.x, tid = threadIdx.x;
  const float* x = in + (size_t)row * 768;
  float v[3]; float s = 0.f, sq = 0.f;
#pragma unroll
  for (int j = 0; j < 3; j++) {
    v[j] = x[tid + j * 256];
    s += v[j]; sq += v[j] * v[j];
  }
  float mean, rstd;
  rowstats(s, sq, red, tid, mean, rstd);
  s = 0.f; sq = 0.f;
#pragma unroll
  for (int j = 0; j < 3; j++) {
    int c = tid + j * 256;
    v[j] = (v[j] - mean) * rstd * g2[c] + b2[c] + xres[(size_t)row * 768 + c];
    r1out[(size_t)row * 768 + c] = v[j];
    s += v[j]; sq += v[j] * v[j];
  }
  rowstats(s, sq, red, tid, mean, rstd);
#pragma unroll
  for (int j = 0; j < 3; j++) {
    int c = tid + j * 256;
    hbout[(size_t)row * 768 + c] = f2bf((v[j] - mean) * rstd * g3[c] + b3[c]);
  }
}

// Fused: xio = LN4(in)*g4+b4 + r1 + xio;  if g1n: hb = bf16(LN1n(xio)*g1n+b1n)
__global__ __launch_bounds__(256) void ln41_k(
    const float* in, const float* g4, const float* b4, const float* r1,
    float* xio, const float* g1n, const float* b1n, bf16* hbout)
{
  __shared__ float red[8];
  int row = blockIdx.x, tid = threadIdx.x;
  const float* x = in + (size_t)row * 768;
  float v[3]; float s = 0.f, sq = 0.f;
#pragma unroll
  for (int j = 0; j < 3; j++) {
    v[j] = x[tid + j * 256];
    s += v[j]; sq += v[j] * v[j];
  }
  float mean, rstd;
  rowstats(s, sq, red, tid, mean, rstd);
  s = 0.f; sq = 0.f;
#pragma unroll
  for (int j = 0; j < 3; j++) {
    int c = tid + j * 256;
    size_t idx = (size_t)row * 768 + c;
    v[j] = (v[j] - mean) * rstd * g4[c] + b4[c] + r1[idx] + xio[idx];
    xio[idx] = v[j];
    s += v[j]; sq += v[j] * v[j];
  }
  if (g1n == nullptr) return;
  rowstats(s, sq, red, tid, mean, rstd);
#pragma unroll
  for (int j = 0; j < 3; j++) {
    int c = tid + j * 256;
    hbout[(size_t)row * 768 + c] = f2bf((v[j] - mean) * rstd * g1n[c] + b1n[c]);
  }
}

// ---------------------------------------------------------------------------
// 128(M)x64(N) MFMA GEMM, manual VGPR-prefetch staging (loads issued before
// the barrier -> software-pipelined vs previous tile's MFMAs).
// 4 waves, each 32(M)x64(N): acc[2][4]. BK=32.
// OUT_MODE: 2 = bf16+GELU, 3 = split-QKV (q,k [B][H][S][D]; v [B][H][D][S]).
// ---------------------------------------------------------------------------
template<int OUT_MODE>
__global__ __launch_bounds__(256) void gemm_mn_k(
    const bf16* __restrict__ A, const bf16* __restrict__ BT,
    const float* __restrict__ bias, void* __restrict__ Cout,
    bf16* __restrict__ qo, bf16* __restrict__ ko, bf16* __restrict__ vo,
    int N, int K, int nTilesN)
{
  __shared__ __align__(16) bf16 Als[128 * 32];
  __shared__ __align__(16) bf16 Bls[64 * 32];
  int tid = threadIdx.x;
  int lane = tid & 63, w = tid >> 6;
  int l15 = lane & 15, l4 = lane >> 4;
  int tm = blockIdx.x / nTilesN;
  int tn = blockIdx.x - tm * nTilesN;
  int m0 = tm << 7, n0 = tn << 6;
  int wm = w << 5;                      // wave's 32 M-rows
  const bf16* Ag = A + (size_t)m0 * K;
  const bf16* Bg = BT + (size_t)n0 * K;
  int srow = tid >> 2;                  // 0..63
  int scol = (tid & 3) * 8;
  f32x4 acc[2][4] = {};
  for (int k0 = 0; k0 < K; k0 += 32) {
    uint4 av0 = *(const uint4*)(Ag + (size_t)srow * K + k0 + scol);
    uint4 av1 = *(const uint4*)(Ag + (size_t)(srow + 64) * K + k0 + scol);
    uint4 bv  = *(const uint4*)(Bg + (size_t)srow * K + k0 + scol);
    __syncthreads();                    // prior LDS reads complete
    *(uint4*)&Als[tid * 8] = av0;
    *(uint4*)&Als[2048 + tid * 8] = av1;
    *(uint4*)&Bls[tid * 8] = bv;
    __syncthreads();
    int ko8 = l4 * 8;
    bf16x8 af[2], bfr[4];
#pragma unroll
    for (int i = 0; i < 2; i++)
      af[i] = *(const bf16x8*)&Als[(wm + i * 16 + l15) * 32 + ko8];
#pragma unroll
    for (int j = 0; j < 4; j++)
      bfr[j] = *(const bf16x8*)&Bls[(j * 16 + l15) * 32 + ko8];
#pragma unroll
    for (int i = 0; i < 2; i++)
#pragma unroll
      for (int j = 0; j < 4; j++)
        acc[i][j] = __builtin_amdgcn_mfma_f32_16x16x32_bf16(af[i], bfr[j], acc[i][j], 0, 0, 0);
  }
#pragma unroll
  for (int i = 0; i < 2; i++) {
    int mbase = m0 + wm + i * 16 + (l4 << 2);
#pragma unroll
    for (int j = 0; j < 4; j++) {
      int n = n0 + j * 16 + l15;
      float bvs = bias[n];
      if (OUT_MODE == 3) {
        int h = n / 192;
        int rm = n - h * 192;
        int d = rm / 3;
        int t = rm - d * 3;
#pragma unroll
        for (int rg = 0; rg < 4; rg++) {
          int m = mbase + rg;
          float val = acc[i][j][rg] + bvs;
          int b = m >> 9, sIdx = m & 511;
          int bh = b * 12 + h;
          if (t == 2)
            vo[(size_t)((bh << 6) + d) * 512 + sIdx] = f2bf(val);       // [B][H][D][S]
          else {
            bf16* dsts = (t == 0) ? qo : ko;
            dsts[(size_t)((bh << 9) + sIdx) * 64 + d] = f2bf(val);      // [B][H][S][D]
          }
        }
      } else {
#pragma unroll
        for (int rg = 0; rg < 4; rg++) {
          int m = mbase + rg;
          float val = acc[i][j][rg] + bvs;
          ((bf16*)Cout)[(size_t)m * N + n] = f2bf(gelu_f(val));
        }
      }
    }
  }
}

// ---------------------------------------------------------------------------
// 64x64 MFMA GEMM, manual VGPR-prefetch staging, fp32 out (proj / FF2).
// ---------------------------------------------------------------------------
__global__ __launch_bounds__(256) void gemm64_k(
    const bf16* __restrict__ A, const bf16* __restrict__ BT,
    const float* __restrict__ bias, float* __restrict__ Cout,
    int N, int K, int nTilesN)
{
  __shared__ __align__(16) bf16 Als[64 * 32];
  __shared__ __align__(16) bf16 Bls[64 * 32];
  int tid = threadIdx.x;
  int lane = tid & 63, w = tid >> 6;
  int l15 = lane & 15, l4 = lane >> 4;
  int tm = blockIdx.x / nTilesN;
  int tn = blockIdx.x - tm * nTilesN;
  int m0 = tm << 6, n0 = tn << 6;
  int wm = (w >> 1) << 5, wn = (w & 1) << 5;
  const bf16* Ag = A + (size_t)m0 * K;
  const bf16* Bg = BT + (size_t)n0 * K;
  int srow = tid >> 2;
  int scol = (tid & 3) * 8;
  f32x4 acc[2][2] = {};
  for (int k0 = 0; k0 < K; k0 += 32) {
    uint4 av = *(const uint4*)(Ag + (size_t)srow * K + k0 + scol);
    uint4 bv = *(const uint4*)(Bg + (size_t)srow * K + k0 + scol);
    __syncthreads();
    *(uint4*)&Als[tid * 8] = av;
    *(uint4*)&Bls[tid * 8] = bv;
    __syncthreads();
    int ko8 = l4 * 8;
    bf16x8 af[2], bfr[2];
#pragma unroll
    for (int i = 0; i < 2; i++)
      af[i] = *(const bf16x8*)&Als[(wm + i * 16 + l15) * 32 + ko8];
#pragma unroll
    for (int j = 0; j < 2; j++)
      bfr[j] = *(const bf16x8*)&Bls[(wn + j * 16 + l15) * 32 + ko8];
#pragma unroll
    for (int i = 0; i < 2; i++)
#pragma unroll
      for (int j = 0; j < 2; j++)
        acc[i][j] = __builtin_amdgcn_mfma_f32_16x16x32_bf16(af[i], bfr[j], acc[i][j], 0, 0, 0);
  }
#pragma unroll
  for (int i = 0; i < 2; i++) {
    int mbase = m0 + wm + i * 16 + (l4 << 2);
#pragma unroll
    for (int j = 0; j < 2; j++) {
      int n = n0 + wn + j * 16 + l15;
      float bvs = bias[n];
#pragma unroll
      for (int rg = 0; rg < 4; rg++)
        Cout[(size_t)(mbase + rg) * N + n] = acc[i][j][rg] + bvs;
    }
  }
}

// ---------------------------------------------------------------------------
// MFMA flash attention. Block = (b,h) x 64 query rows; 4 waves x 16 rows.
// ---------------------------------------------------------------------------
#define PSTR 80
__global__ __launch_bounds__(256) void attn_k(
    const bf16* __restrict__ q, const bf16* __restrict__ k,
    const bf16* __restrict__ vT, bf16* __restrict__ o)
{
  __shared__ __align__(16) bf16 Kls[64 * 64];
  __shared__ __align__(16) bf16 Vls[64 * 64];
  __shared__ __align__(16) bf16 Pls[4][16 * PSTR];
  int tid = threadIdx.x;
  int lane = tid & 63, w = tid >> 6;
  int l15 = lane & 15, l4 = lane >> 4;
  int qt = blockIdx.x & 7;
  int bh = blockIdx.x >> 3;
  size_t base = (size_t)bh * 32768;

  const bf16* qrowp = q + base + (size_t)(qt * 64 + w * 16 + l15) * 64 + l4 * 8;
  bf16x8 qf0 = *(const bf16x8*)qrowp;
  bf16x8 qf1 = *(const bf16x8*)(qrowp + 32);

  float mrow[4] = {-1e30f, -1e30f, -1e30f, -1e30f};
  float lsum[4] = {0.f, 0.f, 0.f, 0.f};
  f32x4 Oacc[4] = {};
  const f32x4 zed = {0.f, 0.f, 0.f, 0.f};
  bf16* pw = &Pls[w][0];

  for (int kt = 0; kt < 8; kt++) {
    __syncthreads();
#pragma unroll
    for (int rep = 0; rep < 2; rep++) {
      int c = tid + rep * 256;
      int row = c >> 3, col8 = (c & 7) * 8;
      *(uint4*)&Kls[row * 64 + col8] =
          *(const uint4*)(k + base + (size_t)(kt * 64 + row) * 64 + col8);
      *(uint4*)&Vls[row * 64 + col8] =
          *(const uint4*)(vT + base + (size_t)row * 512 + kt * 64 + col8);
    }
    __syncthreads();
    f32x4 e[4];
#pragma unroll
    for (int jt = 0; jt < 4; jt++) {
      bf16x8 kf0 = *(const bf16x8*)&Kls[(jt * 16 + l15) * 64 + l4 * 8];
      bf16x8 kf1 = *(const bf16x8*)&Kls[(jt * 16 + l15) * 64 + l4 * 8 + 32];
      e[jt] = __builtin_amdgcn_mfma_f32_16x16x32_bf16(qf0, kf0, zed, 0, 0, 0);
      e[jt] = __builtin_amdgcn_mfma_f32_16x16x32_bf16(qf1, kf1, e[jt], 0, 0, 0);
    }
    float al[4];
#pragma unroll
    for (int rg = 0; rg < 4; rg++) {
      float mn = fmaxf(fmaxf(e[0][rg], e[1][rg]), fmaxf(e[2][rg], e[3][rg]));
#pragma unroll
      for (int off = 1; off < 16; off <<= 1) mn = fmaxf(mn, __shfl_xor(mn, off));
      float mnew = fmaxf(mrow[rg], mn);
      al[rg] = __expf(mrow[rg] - mnew);
      mrow[rg] = mnew;
    }
    float rs[4] = {0.f, 0.f, 0.f, 0.f};
#pragma unroll
    for (int jt = 0; jt < 4; jt++)
#pragma unroll
      for (int rg = 0; rg < 4; rg++) {
        float p = __expf(e[jt][rg] - mrow[rg]);
        rs[rg] += p;
        pw[(l4 * 4 + rg) * PSTR + jt * 16 + l15] = f2bf(p);
      }
#pragma unroll
    for (int rg = 0; rg < 4; rg++) {
#pragma unroll
      for (int off = 1; off < 16; off <<= 1) rs[rg] += __shfl_xor(rs[rg], off);
      lsum[rg] = lsum[rg] * al[rg] + rs[rg];
    }
#pragma unroll
    for (int dt = 0; dt < 4; dt++)
#pragma unroll
      for (int rg = 0; rg < 4; rg++) Oacc[dt][rg] *= al[rg];
    bf16x8 pf0 = *(const bf16x8*)&pw[l15 * PSTR + l4 * 8];
    bf16x8 pf1 = *(const bf16x8*)&pw[l15 * PSTR + l4 * 8 + 32];
#pragma unroll
    for (int dt = 0; dt < 4; dt++) {
      bf16x8 vf0 = *(const bf16x8*)&Vls[(dt * 16 + l15) * 64 + l4 * 8];
      bf16x8 vf1 = *(const bf16x8*)&Vls[(dt * 16 + l15) * 64 + l4 * 8 + 32];
      Oacc[dt] = __builtin_amdgcn_mfma_f32_16x16x32_bf16(pf0, vf0, Oacc[dt], 0, 0, 0);
      Oacc[dt] = __builtin_amdgcn_mfma_f32_16x16x32_bf16(pf1, vf1, Oacc[dt], 0, 0, 0);
    }
  }
  int b = bh / 12, h = bh - b * 12;
#pragma unroll
  for (int rg = 0; rg < 4; rg++) {
    int qrow = qt * 64 + w * 16 + l4 * 4 + rg;
    float inv = SCALE_INV / lsum[rg];
    size_t rowoff = (size_t)(b * 512 + qrow) * 768 + h * 64;
#pragma unroll
    for (int dt = 0; dt < 4; dt++)
      o[rowoff + dt * 16 + l15] = f2bf(Oacc[dt][rg] * inv);
  }
}

// ---------------------------------------------------------------------------
extern "C" void kernel_launch(void* const* d_in, const int* in_sizes, int n_in,
                              void* d_out, int out_size, void* d_ws, size_t ws_size,
                              hipStream_t stream)
{
  const float* x    = (const float*)d_in[0];
  const float* Wqkv = (const float*)d_in[1];
  const float* bqkv = (const float*)d_in[2];
  const float* Wp   = (const float*)d_in[3];
  const float* bp   = (const float*)d_in[4];
  const float* W1   = (const float*)d_in[5];
  const float* b1   = (const float*)d_in[6];
  const float* W2   = (const float*)d_in[7];
  const float* b2   = (const float*)d_in[8];
  const float* g1  = (const float*)d_in[9];
  const float* be1 = (const float*)d_in[10];
  const float* g2  = (const float*)d_in[11];
  const float* be2 = (const float*)d_in[12];
  const float* g3  = (const float*)d_in[13];
  const float* be3 = (const float*)d_in[14];
  const float* g4  = (const float*)d_in[15];
  const float* be4 = (const float*)d_in[16];
  float* xout = (float*)d_out;

  char* ws = (char*)d_ws;
  size_t off = 0;
  auto alloc = [&](size_t bytes) -> char* {
    char* p = ws + off;
    off += (bytes + 255) & ~(size_t)255;
    return p;
  };
  const size_t NTOK = (size_t)M_ROWS * E_DIM;
  bf16*  qb  = (bf16*)alloc(NTOK * 2);
  bf16*  kb  = (bf16*)alloc(NTOK * 2);
  bf16*  vb  = (bf16*)alloc(NTOK * 2);   // V^T [B][H][D][S]
  bf16*  hb  = (bf16*)alloc(NTOK * 2);
  bf16*  ob  = (bf16*)alloc(NTOK * 2);
  bf16*  f1b = (bf16*)alloc((size_t)M_ROWS * FF_DIM * 2);
  float* tmp = (float*)alloc(NTOK * 4);
  float* r1  = (float*)alloc(NTOK * 4);
  bf16*  tq  = (bf16*)alloc((size_t)LAYERS * 768 * 2304 * 2);
  bf16*  tp  = (bf16*)alloc((size_t)LAYERS * 768 * 768 * 2);
  bf16*  t1  = (bf16*)alloc((size_t)LAYERS * 768 * 3072 * 2);
  bf16*  t2  = (bf16*)alloc((size_t)LAYERS * 3072 * 768 * 2);
  if (off > ws_size) {
    hipMemsetAsync(d_out, 0x7f, (size_t)out_size * 4, stream);
    return;
  }

  hipMemcpyAsync(d_out, x, (size_t)out_size * 4, hipMemcpyDeviceToDevice, stream);

  transpose_k<<<1728 * LAYERS, 256, 0, stream>>>(Wqkv, Wp, W1, W2, tq, tp, t1, t2);
  ln_k<<<2048, 256, 0, stream>>>(xout, g1, be1, hb);

  for (int l = 0; l < LAYERS; l++) {
    const bf16* tql = tq + (size_t)l * 768 * 2304;
    const bf16* tpl = tp + (size_t)l * 768 * 768;
    const bf16* t1l = t1 + (size_t)l * 768 * 3072;
    const bf16* t2l = t2 + (size_t)l * 3072 * 768;

    // qkv = hb @ Wqkv + bqkv  (16 x 36 = 576 blocks)
    gemm_mn_k<3><<<16 * 36, 256, 0, stream>>>(hb, tql, bqkv + (size_t)l * QKV_DIM,
                                              nullptr, qb, kb, vb, QKV_DIM, 768, 36);
    attn_k<<<384, 256, 0, stream>>>(qb, kb, vb, ob);
    // proj: tmp = ob @ Wp + bp  (384 blocks)
    gemm64_k<<<32 * 12, 256, 0, stream>>>(ob, tpl, bp + (size_t)l * 768,
                                          tmp, 768, 768, 12);
    ln23_k<<<2048, 256, 0, stream>>>(tmp, g2 + l * 768, be2 + l * 768, xout,
                                     r1, g3 + l * 768, be3 + l * 768, hb);
    // f1 = gelu(hb @ W1 + b1)  (16 x 48 = 768 blocks)
    gemm_mn_k<2><<<16 * 48, 256, 0, stream>>>(hb, t1l, b1 + (size_t)l * FF_DIM,
                                              f1b, nullptr, nullptr, nullptr, FF_DIM, 768, 48);
    // tmp = f1 @ W2 + b2  (384 blocks)
    gemm64_k<<<32 * 12, 256, 0, stream>>>(f1b, t2l, b2 + (size_t)l * 768,
                                          tmp, 768, 3072, 12);
    const float* g1n  = (l + 1 < LAYERS) ? g1 + (l + 1) * 768 : nullptr;
    const float* be1n = (l + 1 < LAYERS) ? be1 + (l + 1) * 768 : nullptr;
    ln41_k<<<2048, 256, 0, stream>>>(tmp, g4 + l * 768, be4 + l * 768, r1,
                                     xout, g1n, be1n, hb);
  }
}